// Round 17
// baseline (471.411 us; speedup 1.0000x reference)
//
#include <hip/hip_runtime.h>
#include <cstdint>
#include <cstddef>

#define B_    4
#define N_    1024
#define P_    128
#define D_    512
#define NH_   8
#define QKVW  4608   // merged QKV row width

typedef unsigned short ushort_t;
typedef short short8 __attribute__((ext_vector_type(8)));
typedef float f32x4 __attribute__((ext_vector_type(4)));
typedef ushort_t ushort4_t __attribute__((ext_vector_type(4)));

__device__ inline ushort_t f2bf(float f) {
  union { float fp; unsigned int u; } v; v.fp = f;
  unsigned int r = v.u + 0x7fffu + ((v.u >> 16) & 1u);
  return (ushort_t)(r >> 16);
}
__device__ inline float bf2f(ushort_t u) {
  union { unsigned int i; float f; } v; v.i = ((unsigned int)u) << 16;
  return v.f;
}

__device__ __forceinline__ void gll16(const ushort_t* g, ushort_t* l) {
  __builtin_amdgcn_global_load_lds(
      (const __attribute__((address_space(1))) void*)g,
      (__attribute__((address_space(3))) void*)l, 16, 0, 0);
}

// ---------------------------------------------------------------------------
// P0 mega-kernel: fused casts + caow-transpose + bias-combine(ca) +
// bias-merge + combined-bias + ln1.  Block ranges:
// [0,7552) casts (13 tensors; caow handled by transpose segment)
// [7552,7616) caow fp32 -> bf16 TRANSPOSED (64x 64x64 tiles)
// [7616,7618) bc = casw @ caob + casb (512 dots)
// [7618,7636) biasmerge3  [7636,11732) biascomb  [11732,15828) ln1
// ---------------------------------------------------------------------------
__device__ inline void cast8(const float* __restrict__ s, ushort_t* __restrict__ d,
                             unsigned i) {
  const float* sp = s + (size_t)i * 8;
  short8 o;
#pragma unroll
  for (int j = 0; j < 8; ++j) o[j] = (short)f2bf(sp[j]);
  *(short8*)(d + (size_t)i * 8) = o;
}

__global__ __launch_bounds__(256) void p0_fused(
    const float* s0, ushort_t* d0,  const float* s1, ushort_t* d1,
    const float* s2, ushort_t* d2,  const float* s3, ushort_t* d3,
    const float* s4, ushort_t* d4,  const float* s5, ushort_t* d5,
    const float* s6, ushort_t* d6,
    const float* caow, ushort_t* caowT,
    const float* s8, ushort_t* d8,  const float* s9, ushort_t* d9,
    const float* s10, ushort_t* d10, const float* s11, ushort_t* d11,
    const float* s12, ushort_t* d12, const float* s13, ushort_t* d13,
    const float* caob, const float* casb, float* bcF,
    const float* bq, const float* bk, const float* bv, float* bqkv,
    const float* Db, const float* rbf, const int* mask, ushort_t* biasc,
    const float* Hx, const float* g1, const float* b1, ushort_t* hn)
{
  const int blk = blockIdx.x;
  const int tid = threadIdx.x;

  if (blk < 7552) {
    unsigned i = blk * 256 + tid;
#define SEG(s, d, n8) if (i < (n8)) { cast8(s, d, i); return; } i -= (n8);
    SEG(s0, d0, 131072u)   // Wq
    SEG(s1, d1, 131072u)   // Wk
    SEG(s2, d2, 32768u)    // Wv
    SEG(s3, d3, 32768u)    // Wvv
    SEG(s4, d4, 32768u)    // Wo
    SEG(s5, d5, 32768u)    // Wvo
    SEG(s6, d6, 98304u)    // caw
    SEG(s8, d8, 32768u)    // casw
    SEG(s9, d9, 65536u)    // flv
    SEG(s10, d10, 262144u) // fw1
    SEG(s11, d11, 262144u) // fw2
    SEG(s12, d12, 32768u)  // prompt
    SEG(s13, d13, 786432u) // V
#undef SEG
    return;
  }
  if (blk < 7616) {
    // transpose-cast caow: caowT[j][i] = bf16(caow[i][j])
    __shared__ float tf[64][65];
    int tile = blk - 7552, bi = tile >> 3, bj = tile & 7;
    int r = tid >> 2, c0 = (tid & 3) * 16;
    const float* src = caow + (size_t)(bi * 64 + r) * 512 + bj * 64 + c0;
#pragma unroll
    for (int c = 0; c < 16; ++c) tf[r][c0 + c] = src[c];
    __syncthreads();
    ushort_t* dst = caowT + (size_t)(bj * 64 + r) * 512 + bi * 64 + c0;
#pragma unroll
    for (int c = 0; c < 16; ++c) dst[c] = f2bf(tf[c0 + c][r]);
    return;
  }
  if (blk < 7618) {
    // bc[i] = dot(casw[i,:], caob) + casb[i]   (fp32 inputs)
    int i = (blk - 7616) * 256 + tid;
    const float* row = s8 + (size_t)i * 512;
    float acc = 0.f;
    for (int k = 0; k < 512; ++k) acc += row[k] * caob[k];
    bcF[i] = acc + casb[i];
    return;
  }
  if (blk < 7636) {
    int i = (blk - 7618) * 256 + tid;
    if (i < 4608)
      bqkv[i] = (i < 2048) ? bq[i] : (i < 4096) ? bk[i - 2048] : bv[i - 4096];
    return;
  }
  if (blk < 11732) {
    size_t i = (size_t)(blk - 7636) * 256 + tid;
    size_t e = i * 4;
    int b  = (int)(e >> 20);
    int m0 = (int)(e & 1023);
    float4 r = *(const float4*)(rbf + e);
    float4 d = *(const float4*)(Db + e);
    const int* mp = mask + b * 1024 + m0;
    ushort4_t o;
    o.x = f2bf(mp[0] ? r.x + d.x : -1e30f);
    o.y = f2bf(mp[1] ? r.y + d.y : -1e30f);
    o.z = f2bf(mp[2] ? r.z + d.z : -1e30f);
    o.w = f2bf(mp[3] ? r.w + d.w : -1e30f);
    *(ushort4_t*)(biasc + e) = o;
    return;
  }
  {
    int row = blk - 11732;
    const float* xr = Hx + (size_t)row * D_;
    float a = xr[tid], c = xr[tid + 256];
    float s = a + c, sq = a * a + c * c;
#pragma unroll
    for (int off = 32; off >= 1; off >>= 1) {
      s  += __shfl_xor(s, off);
      sq += __shfl_xor(sq, off);
    }
    __shared__ float red[8];
    int w = tid >> 6, lane = tid & 63;
    if (lane == 0) { red[w] = s; red[4 + w] = sq; }
    __syncthreads();
    float st  = red[0] + red[1] + red[2] + red[3];
    float sqt = red[4] + red[5] + red[6] + red[7];
    float mean = st * (1.0f / D_);
    float var  = sqt * (1.0f / D_) - mean * mean;
    float inv  = rsqrtf(var + 1e-5f);
    hn[(size_t)row * 512 + tid]       = f2bf((a - mean) * inv * g1[tid] + b1[tid]);
    hn[(size_t)row * 512 + tid + 256] = f2bf((c - mean) * inv * g1[tid + 256] + b1[tid + 256]);
  }
}

// ---------------------------------------------------------------------------
// LayerNorm (fp32 in, bf16 out)
// ---------------------------------------------------------------------------
__global__ __launch_bounds__(256) void ln_kernel(
    const float* __restrict__ x, const float* __restrict__ g,
    const float* __restrict__ bb, ushort_t* __restrict__ y, int ostride)
{
  int row = blockIdx.x;
  int t = threadIdx.x;
  const float* xr = x + (size_t)row * D_;
  float a = xr[t], c = xr[t + 256];
  float s = a + c, sq = a * a + c * c;
#pragma unroll
  for (int off = 32; off >= 1; off >>= 1) {
    s  += __shfl_xor(s, off);
    sq += __shfl_xor(sq, off);
  }
  __shared__ float red[8];
  int w = t >> 6, lane = t & 63;
  if (lane == 0) { red[w] = s; red[4 + w] = sq; }
  __syncthreads();
  float st  = red[0] + red[1] + red[2] + red[3];
  float sqt = red[4] + red[5] + red[6] + red[7];
  float mean = st * (1.0f / D_);
  float var  = sqt * (1.0f / D_) - mean * mean;
  float inv  = rsqrtf(var + 1e-5f);
  y[(size_t)row * ostride + t]       = f2bf((a - mean) * inv * g[t] + bb[t]);
  y[(size_t)row * ostride + t + 256] = f2bf((c - mean) * inv * g[t + 256] + bb[t + 256]);
}

// ---------------------------------------------------------------------------
// Fused ln3 + vnorm
// ---------------------------------------------------------------------------
__global__ __launch_bounds__(256) void ln3_vnorm_fused(
    const float* __restrict__ x, const float* __restrict__ g,
    const float* __restrict__ bb, const ushort_t* __restrict__ Vp,
    ushort_t* __restrict__ scal)
{
  const int blk = blockIdx.x;
  const int t = threadIdx.x;
  if (blk < 4096) {
    int row = blk;
    const float* xr = x + (size_t)row * D_;
    float a = xr[t], c = xr[t + 256];
    float s = a + c, sq = a * a + c * c;
#pragma unroll
    for (int off = 32; off >= 1; off >>= 1) {
      s  += __shfl_xor(s, off);
      sq += __shfl_xor(sq, off);
    }
    __shared__ float red[8];
    int w = t >> 6, lane = t & 63;
    if (lane == 0) { red[w] = s; red[4 + w] = sq; }
    __syncthreads();
    float st  = red[0] + red[1] + red[2] + red[3];
    float sqt = red[4] + red[5] + red[6] + red[7];
    float mean = st * (1.0f / D_);
    float var  = sqt * (1.0f / D_) - mean * mean;
    float inv  = rsqrtf(var + 1e-5f);
    scal[(size_t)row * 1024 + t]       = f2bf((a - mean) * inv * g[t] + bb[t]);
    scal[(size_t)row * 1024 + t + 256] = f2bf((c - mean) * inv * g[t + 256] + bb[t + 256]);
    return;
  }
  size_t i = (size_t)(blk - 4096) * 256 + t;
  size_t bn = i >> 9; int d = (int)(i & 511);
  size_t base = bn * 3 * 1024 + d;
  float a = bf2f(Vp[base]);
  float b = bf2f(Vp[base + 1024]);
  float c = bf2f(Vp[base + 2048]);
  scal[bn * 1024 + 512 + d] = f2bf(sqrtf(a * a + b * b + c * c));
}

// ---------------------------------------------------------------------------
// bf16 MFMA GEMM, 128x128 tile (gll16 staging + swizzle + XCD remap)
// flags: 1=bias 2=res 4=silu 8=write fp32 16=write bf16
// ---------------------------------------------------------------------------
__global__ __launch_bounds__(256) void gemm_bf16(
    const ushort_t* __restrict__ A, const ushort_t* __restrict__ W,
    const float* __restrict__ bias, const float* __restrict__ res,
    float* __restrict__ Cf, ushort_t* __restrict__ Cb,
    int M, int N, int K, int flags)
{
  __shared__ __align__(16) ushort_t Al[128 * 32];
  __shared__ __align__(16) ushort_t Wl[128 * 32];
  const int t = threadIdx.x;
  const int wv = t >> 6, lane = t & 63, lr = lane & 15, lk = lane >> 4;
  const int wr = wv >> 1, wc = wv & 1;

  const int gx = gridDim.x;
  const int lid = blockIdx.y * gx + blockIdx.x;
  const int cpx = (gx * gridDim.y) >> 3;
  const int nlid = (lid & 7) * cpx + (lid >> 3);
  const size_t row0 = (size_t)(nlid / gx) * 128;
  const size_t col0 = (size_t)(nlid % gx) * 128;

  const int srow = 32 * wv + (lane >> 2);
  const int scol = (((lane & 3) ^ ((lane >> 3) & 3))) * 8;
  const ushort_t* ApG = A + (row0 + srow) * (size_t)K + scol;
  const ushort_t* WpG = W + (col0 + srow) * (size_t)K + scol;
  ushort_t* AlD = Al + (size_t)(32 * wv) * 32;
  ushort_t* WlD = Wl + (size_t)(32 * wv) * 32;
  const size_t K16 = (size_t)16 * K;

  f32x4 acc[4][4];
#pragma unroll
  for (int i = 0; i < 4; ++i)
#pragma unroll
    for (int j = 0; j < 4; ++j) acc[i][j] = f32x4{0.f, 0.f, 0.f, 0.f};

  const int sx = (lr >> 1) & 3;

  for (int k0 = 0; k0 < K; k0 += 32) {
    __syncthreads();
    gll16(ApG + k0,       AlD);
    gll16(ApG + k0 + K16, AlD + 512);
    gll16(WpG + k0,       WlD);
    gll16(WpG + k0 + K16, WlD + 512);
    __syncthreads();
    short8 af[4], bf[4];
#pragma unroll
    for (int i = 0; i < 4; ++i)
      af[i] = *(const short8*)&Al[(wr * 64 + i * 16 + lr) * 32 + ((lk ^ sx) << 3)];
#pragma unroll
    for (int j = 0; j < 4; ++j)
      bf[j] = *(const short8*)&Wl[(wc * 64 + j * 16 + lr) * 32 + ((lk ^ sx) << 3)];
#pragma unroll
    for (int i = 0; i < 4; ++i)
#pragma unroll
      for (int j = 0; j < 4; ++j)
        acc[i][j] = __builtin_amdgcn_mfma_f32_16x16x32_bf16(af[i], bf[j], acc[i][j], 0, 0, 0);
  }

  const int orow = wr * 64 + lk * 4, ocol = wc * 64 + lr;
#pragma unroll
  for (int i = 0; i < 4; ++i) {
#pragma unroll
    for (int j = 0; j < 4; ++j) {
      size_t colb = col0 + ocol + j * 16;
      float bv = (flags & 1) ? bias[colb] : 0.f;
#pragma unroll
      for (int r = 0; r < 4; ++r) {
        size_t rowg = row0 + orow + i * 16 + r;
        float v = acc[i][j][r] + bv;
        if (flags & 4) v = v / (1.f + __expf(-v));
        if (flags & 2) v += res[rowg * N + colb];
        if (flags & 8)  Cf[rowg * N + colb] = v;
        if (flags & 16) Cb[rowg * N + colb] = f2bf(v);
      }
    }
  }
}

// ---------------------------------------------------------------------------
// Small-M GEMM variant: BM=64 x BN=128.  flags 32 = fused "final" epilogue.
// ---------------------------------------------------------------------------
__global__ __launch_bounds__(256) void gemm_bf16_sm(
    const ushort_t* __restrict__ A, const ushort_t* __restrict__ W,
    const float* __restrict__ bias, const float* __restrict__ res,
    float* __restrict__ Cf, ushort_t* __restrict__ Cb,
    const ushort_t* __restrict__ Vp, const float* __restrict__ Vnw,
    int M, int N, int K, int flags)
{
  __shared__ __align__(16) ushort_t Al[64 * 32];
  __shared__ __align__(16) ushort_t Wl[128 * 32];
  const int t = threadIdx.x;
  const int wv = t >> 6, lane = t & 63, lr = lane & 15, lk = lane >> 4;
  const int wr = wv >> 1, wc = wv & 1;

  const int gx = gridDim.x;
  const int lid = blockIdx.y * gx + blockIdx.x;
  const int cpx = (gx * gridDim.y) >> 3;
  const int nlid = (lid & 7) * cpx + (lid >> 3);
  const size_t row0 = (size_t)(nlid / gx) * 64;
  const size_t col0 = (size_t)(nlid % gx) * 128;

  const int scol = (((lane & 3) ^ ((lane >> 3) & 3))) * 8;
  const int srowA = 16 * wv + (lane >> 2);
  const int srowW = 32 * wv + (lane >> 2);
  const ushort_t* ApG = A + (row0 + srowA) * (size_t)K + scol;
  const ushort_t* WpG = W + (col0 + srowW) * (size_t)K + scol;
  ushort_t* AlD = Al + (size_t)(16 * wv) * 32;
  ushort_t* WlD = Wl + (size_t)(32 * wv) * 32;
  const size_t K16 = (size_t)16 * K;

  f32x4 acc[2][4];
#pragma unroll
  for (int i = 0; i < 2; ++i)
#pragma unroll
    for (int j = 0; j < 4; ++j) acc[i][j] = f32x4{0.f, 0.f, 0.f, 0.f};

  const int sx = (lr >> 1) & 3;

  for (int k0 = 0; k0 < K; k0 += 32) {
    __syncthreads();
    gll16(ApG + k0,       AlD);
    gll16(WpG + k0,       WlD);
    gll16(WpG + k0 + K16, WlD + 512);
    __syncthreads();
    short8 af[2], bf[4];
#pragma unroll
    for (int i = 0; i < 2; ++i)
      af[i] = *(const short8*)&Al[(wr * 32 + i * 16 + lr) * 32 + ((lk ^ sx) << 3)];
#pragma unroll
    for (int j = 0; j < 4; ++j)
      bf[j] = *(const short8*)&Wl[(wc * 64 + j * 16 + lr) * 32 + ((lk ^ sx) << 3)];
#pragma unroll
    for (int i = 0; i < 2; ++i)
#pragma unroll
      for (int j = 0; j < 4; ++j)
        acc[i][j] = __builtin_amdgcn_mfma_f32_16x16x32_bf16(af[i], bf[j], acc[i][j], 0, 0, 0);
  }

  const int orow = wr * 32 + lk * 4, ocol = wc * 64 + lr;
#pragma unroll
  for (int i = 0; i < 2; ++i) {
#pragma unroll
    for (int j = 0; j < 4; ++j) {
      size_t colb = col0 + ocol + j * 16;
      float bv = (flags & 1) ? bias[colb] : 0.f;
#pragma unroll
      for (int r = 0; r < 4; ++r) {
        size_t rowg = row0 + orow + i * 16 + r;
        float v = acc[i][j][r] + bv;
        if (flags & 4) v = v / (1.f + __expf(-v));
        if (flags & 32) {
          if (colb < 512) {
            Cf[rowg * 512 + colb] = v + res[rowg * 512 + colb];
          } else {
            int dd = (int)colb - 512;
            float* outV = Cf + (size_t)4096 * 512;
#pragma unroll
            for (int c = 0; c < 3; ++c) {
              size_t vi = (rowg * 3 + c) * 512 + dd;
              outV[vi] = v * bf2f(Vp[(rowg * 3 + c) * 1024 + 512 + dd]) + Vnw[vi];
            }
          }
          continue;
        }
        if (flags & 2) v += res[rowg * N + colb];
        if (flags & 8)  Cf[rowg * N + colb] = v;
        if (flags & 16) Cb[rowg * N + colb] = f2bf(v);
      }
    }
  }
}

// ---------------------------------------------------------------------------
// Build VT[b][h][dcat(256)][n(1024)] bf16.
// ---------------------------------------------------------------------------
__global__ __launch_bounds__(256) void vt_build(
    const ushort_t* __restrict__ QKVb, const ushort_t* __restrict__ VVTb,
    ushort_t* __restrict__ VT)
{
  const int bh = blockIdx.z, b = bh >> 3, h = bh & 7;
  const int n0 = blockIdx.x * 64, dt = blockIdx.y;
  __shared__ __align__(16) ushort_t tile[64][72];
  const int t = threadIdx.x;
  {
    int r = t >> 2, c0 = (t & 3) * 16;
    const ushort_t* src = (dt == 0)
      ? QKVb + ((size_t)(b * 1024 + n0 + r)) * QKVW + 4096 + h * 64 + c0
      : VVTb + (((size_t)(b * 1024 + n0 + r)) * 3 + (dt - 1)) * 512 + h * 64 + c0;
    *(short8*)&tile[r][c0]     = *(const short8*)src;
    *(short8*)&tile[r][c0 + 8] = *(const short8*)(src + 8);
  }
  __syncthreads();
  {
    int d = t >> 2, nc = (t & 3) * 16;
    short8 o0, o1;
#pragma unroll
    for (int i = 0; i < 8; ++i) { o0[i] = tile[nc + i][d]; o1[i] = tile[nc + 8 + i][d]; }
    ushort_t* dst = VT + ((size_t)bh * 256 + dt * 64 + d) * 1024 + n0 + nc;
    *(short8*)dst = o0;
    *(short8*)(dst + 8) = o1;
  }
}

// ---------------------------------------------------------------------------
// Fused self-attention — r13 known-good body (KVBLK=32, pitch-268 K tile).
// ---------------------------------------------------------------------------
__global__ __launch_bounds__(256) void attn_mfma(
    const ushort_t* __restrict__ QKg, const ushort_t* __restrict__ VTg,
    const ushort_t* __restrict__ biasb,
    ushort_t* __restrict__ HRESb, ushort_t* __restrict__ VRESb)
{
  const int blk = blockIdx.x;
  const int bi = blk >> 3;
  const int bh = (blk & 7) * 4 + (bi >> 4), b = bh >> 3, h = bh & 7;
  const int q0 = (bi & 15) * 64;
  const int t = threadIdx.x, w = t >> 6, lane = t & 63, lr = lane & 15, lk = lane >> 4;

  __shared__ __align__(16) ushort_t Kl[32][268];
  __shared__ __align__(16) ushort_t Vl[256][40];
  __shared__ __align__(16) ushort_t Pl[4][16][40];

  short8 qf[8];
  {
    const ushort_t* qb = QKg + ((size_t)(b * 1024 + q0 + w * 16 + lr)) * QKVW + h * 256;
#pragma unroll
    for (int s = 0; s < 8; ++s) qf[s] = *(const short8*)(qb + s * 32 + lk * 8);
  }
  f32x4 o[16];
#pragma unroll
  for (int i = 0; i < 16; ++i) o[i] = f32x4{0.f, 0.f, 0.f, 0.f};
  float mrow[4] = {-1e30f, -1e30f, -1e30f, -1e30f};
  float lsum[4] = {0.f, 0.f, 0.f, 0.f};
  const int qrow = q0 + w * 16 + lk * 4;

  const int krow = t >> 3, kc = (t & 7) * 32;
  const ushort_t* ksrc = QKg + ((size_t)(b * 1024 + krow)) * QKVW + 2048 + h * 256 + kc;
  const ushort_t* vsrc = VTg + ((size_t)bh * 256 + t) * 1024;
  const int vrot = (t >> 3) & 3;

  for (int k0 = 0; k0 < 1024; k0 += 32) {
    __syncthreads();
    {
      const ushort_t* ks = ksrc + (size_t)k0 * QKVW;
#pragma unroll
      for (int c = 0; c < 4; ++c)
        *(short8*)&Kl[krow][kc + c * 8] = *(const short8*)(ks + c * 8);
#pragma unroll
      for (int c = 0; c < 4; ++c) {
        int cc = (c + vrot) & 3;
        *(short8*)&Vl[t][cc * 8] = *(const short8*)(vsrc + k0 + cc * 8);
      }
    }
    __syncthreads();

    f32x4 s2[2];
    s2[0] = f32x4{0.f, 0.f, 0.f, 0.f};
    s2[1] = f32x4{0.f, 0.f, 0.f, 0.f};
    __builtin_amdgcn_s_setprio(1);
#pragma unroll
    for (int ks = 0; ks < 8; ++ks) {
#pragma unroll
      for (int j = 0; j < 2; ++j) {
        short8 kf = *(const short8*)&Kl[j * 16 + lr][ks * 32 + lk * 8];
        s2[j] = __builtin_amdgcn_mfma_f32_16x16x32_bf16(qf[ks], kf, s2[j], 0, 0, 0);
      }
    }
    __builtin_amdgcn_s_setprio(0);

    float sv[2][4];
    const ushort_t* bp = biasb + ((size_t)b << 20) + (size_t)qrow * 1024 + k0 + lr;
#pragma unroll
    for (int r = 0; r < 4; ++r) {
      sv[0][r] = s2[0][r] * 0.0625f + bf2f(bp[r * 1024]);
      sv[1][r] = s2[1][r] * 0.0625f + bf2f(bp[r * 1024 + 16]);
    }
    float pm[4], need = -1e30f;
#pragma unroll
    for (int r = 0; r < 4; ++r) {
      float m2 = fmaxf(sv[0][r], sv[1][r]);
      m2 = fmaxf(m2, __shfl_xor(m2, 1));
      m2 = fmaxf(m2, __shfl_xor(m2, 2));
      m2 = fmaxf(m2, __shfl_xor(m2, 4));
      m2 = fmaxf(m2, __shfl_xor(m2, 8));
      pm[r] = m2;
      need = fmaxf(need, m2 - mrow[r]);
    }
    if (!__all(need <= 8.f)) {
#pragma unroll
      for (int r = 0; r < 4; ++r) {
        float mn = fmaxf(mrow[r], pm[r]);
        float al = __expf(mrow[r] - mn);
        mrow[r] = mn;
        lsum[r] *= al;
#pragma unroll
        for (int d = 0; d < 16; ++d) o[d][r] *= al;
      }
    }
#pragma unroll
    for (int r = 0; r < 4; ++r) {
      float p0 = __expf(sv[0][r] - mrow[r]);
      float p1 = __expf(sv[1][r] - mrow[r]);
      float rs = p0 + p1;
      rs += __shfl_xor(rs, 1); rs += __shfl_xor(rs, 2);
      rs += __shfl_xor(rs, 4); rs += __shfl_xor(rs, 8);
      lsum[r] += rs;
      Pl[w][lk * 4 + r][lr]      = f2bf(p0);
      Pl[w][lk * 4 + r][16 + lr] = f2bf(p1);
    }
    short8 pf = *(const short8*)&Pl[w][lr][lk * 8];
    __builtin_amdgcn_s_setprio(1);
#pragma unroll
    for (int d = 0; d < 16; ++d) {
      short8 vf = *(const short8*)&Vl[d * 16 + lr][lk * 8];
      o[d] = __builtin_amdgcn_mfma_f32_16x16x32_bf16(pf, vf, o[d], 0, 0, 0);
    }
    __builtin_amdgcn_s_setprio(0);
  }

  float inv[4];
#pragma unroll
  for (int r = 0; r < 4; ++r) inv[r] = 1.f / lsum[r];
#pragma unroll
  for (int d = 0; d < 16; ++d) {
    int dcat = d * 16 + lr;
#pragma unroll
    for (int r = 0; r < 4; ++r) {
      float v = o[d][r] * inv[r];
      int n = qrow + r;
      if (dcat < 64)
        HRESb[((size_t)b * 1024 + n) * 512 + h * 64 + dcat] = f2bf(v);
      else {
        int c = (dcat - 64) >> 6, jj = (dcat - 64) & 63;
        VRESb[(((size_t)b * 1024 + n) * 3 + c) * 512 + h * 64 + jj] = f2bf(v);
      }
    }
  }
}

// ---------------------------------------------------------------------------
// Cross-attention, bf16 MFMA.
// ---------------------------------------------------------------------------
__global__ __launch_bounds__(256) void attn_cross_mfma(
    const ushort_t* __restrict__ Qb, const ushort_t* __restrict__ KVb,
    ushort_t* __restrict__ COb)
{
  const int bh = blockIdx.y, b = bh >> 3, h = bh & 7;
  const int q0 = blockIdx.x * 64;
  const int t = threadIdx.x, w = t >> 6, lane = t & 63, lr = lane & 15, lk = lane >> 4;

  __shared__ __align__(16) ushort_t Kl[128][72];
  __shared__ __align__(16) ushort_t Vt[64][136];
  __shared__ __align__(16) ushort_t Pl[4][16][136];

  {
    int p = t >> 1, c0 = (t & 1) * 32;
    const ushort_t* kp = KVb + ((size_t)b * 128 + p) * 1024 + h * 64 + c0;
#pragma unroll
    for (int i = 0; i < 4; ++i) {
      short8 kv = *(const short8*)(kp + i * 8);
      *(short8*)&Kl[p][c0 + i * 8] = kv;
      short8 vv = *(const short8*)(kp + 512 + i * 8);
#pragma unroll
      for (int jj = 0; jj < 8; ++jj) Vt[c0 + i * 8 + jj][p] = (ushort_t)vv[jj];
    }
  }
  __syncthreads();

  short8 qf[2];
  {
    const ushort_t* qp = Qb + ((size_t)b * 1024 + q0 + w * 16 + lr) * 512 + h * 64;
    qf[0] = *(const short8*)(qp + lk * 8);
    qf[1] = *(const short8*)(qp + 32 + lk * 8);
  }

  f32x4 s[8];
#pragma unroll
  for (int j = 0; j < 8; ++j) s[j] = f32x4{0.f, 0.f, 0.f, 0.f};
#pragma unroll
  for (int ks = 0; ks < 2; ++ks)
#pragma unroll
    for (int j = 0; j < 8; ++j) {
      short8 kf = *(const short8*)&Kl[j * 16 + lr][ks * 32 + lk * 8];
      s[j] = __builtin_amdgcn_mfma_f32_16x16x32_bf16(qf[ks], kf, s[j], 0, 0, 0);
    }

  float linv[4];
#pragma unroll
  for (int r = 0; r < 4; ++r) {
    float sc[8];
#pragma unroll
    for (int j = 0; j < 8; ++j) sc[j] = s[j][r] * 0.125f;
    float mx = sc[0];
#pragma unroll
    for (int j = 1; j < 8; ++j) mx = fmaxf(mx, sc[j]);
    mx = fmaxf(mx, __shfl_xor(mx, 1));
    mx = fmaxf(mx, __shfl_xor(mx, 2));
    mx = fmaxf(mx, __shfl_xor(mx, 4));
    mx = fmaxf(mx, __shfl_xor(mx, 8));
    float rs = 0.f;
#pragma unroll
    for (int j = 0; j < 8; ++j) {
      float p = __expf(sc[j] - mx);
      rs += p;
      Pl[w][lk * 4 + r][j * 16 + lr] = f2bf(p);
    }
    rs += __shfl_xor(rs, 1); rs += __shfl_xor(rs, 2);
    rs += __shfl_xor(rs, 4); rs += __shfl_xor(rs, 8);
    linv[r] = 1.f / rs;
  }
  __syncthreads();

  f32x4 o[4];
#pragma unroll
  for (int d = 0; d < 4; ++d) o[d] = f32x4{0.f, 0.f, 0.f, 0.f};
#pragma unroll
  for (int ks = 0; ks < 4; ++ks) {
    short8 pf = *(const short8*)&Pl[w][lr][ks * 32 + lk * 8];
#pragma unroll
    for (int d = 0; d < 4; ++d) {
      short8 vf = *(const short8*)&Vt[d * 16 + lr][ks * 32 + lk * 8];
      o[d] = __builtin_amdgcn_mfma_f32_16x16x32_bf16(pf, vf, o[d], 0, 0, 0);
    }
  }

#pragma unroll
  for (int d = 0; d < 4; ++d)
#pragma unroll
    for (int r = 0; r < 4; ++r) {
      int n = q0 + w * 16 + lk * 4 + r;
      COb[((size_t)b * 1024 + n) * 512 + h * 64 + d * 16 + lr] = f2bf(o[d][r] * linv[r]);
    }
}

// ---------------------------------------------------------------------------
extern "C" void kernel_launch(void* const* d_in, const int* in_sizes, int n_in,
                              void* d_out, int out_size, void* d_ws, size_t ws_size,
                              hipStream_t stream)
{
  const float* H      = (const float*)d_in[0];
  const float* V      = (const float*)d_in[1];
  const float* Db     = (const float*)d_in[2];
  const float* rbf    = (const float*)d_in[3];
  const float* prompt = (const float*)d_in[4];
  const float* Wq  = (const float*)d_in[5];
  const float* bq  = (const float*)d_in[6];
  const float* Wk  = (const float*)d_in[7];
  const float* bk  = (const float*)d_in[8];
  const float* Wv  = (const float*)d_in[9];
  const float* bv  = (const float*)d_in[10];
  const float* Wvv = (const float*)d_in[11];
  const float* Wo  = (const float*)d_in[12];
  const float* bo  = (const float*)d_in[13];
  const float* Wvo = (const float*)d_in[14];
  const float* ln1g = (const float*)d_in[15];
  const float* ln1b = (const float*)d_in[16];
  const float* caw  = (const float*)d_in[17];
  const float* cab  = (const float*)d_in[18];
  const float* caow = (const float*)d_in[19];
  const float* caob = (const float*)d_in[20];
  const float* casw = (const float*)d_in[21];
  const float* casb = (const float*)d_in[22];
  const float* ln2g = (const float*)d_in[23];
  const float* ln2b = (const float*)d_in[24];
  const float* flv  = (const float*)d_in[25];
  const float* fw1  = (const float*)d_in[26];
  const float* fb1  = (const float*)d_in[27];
  const float* fw2  = (const float*)d_in[28];
  const float* fb2  = (const float*)d_in[29];
  const float* ln3g = (const float*)d_in[30];
  const float* ln3b = (const float*)d_in[31];
  const int*   mask = (const int*)d_in[32];

  char* wsb = (char*)d_ws;
  float* out = (float*)d_out;

  // offsets in 0.5 MiB units; lifetimes audited; max 256 u = 128 MiB
#define HMB(x) ((size_t)(x) << 19)
  ushort_t* Wqkvb = (ushort_t*)(wsb + HMB(0));    // 9 u
  ushort_t* Wvvb  = (ushort_t*)(wsb + HMB(9));
  ushort_t* Wob   = (ushort_t*)(wsb + HMB(10));
  ushort_t* Wvob  = (ushort_t*)(wsb + HMB(11));
  ushort_t* cawb  = (ushort_t*)(wsb + HMB(12));
  ushort_t* caowTb= (ushort_t*)(wsb + HMB(15));   // caow^T bf16 (P0 -> combine)
  ushort_t* caswb = (ushort_t*)(wsb + HMB(16));
  ushort_t* flvb  = (ushort_t*)(wsb + HMB(17));
  ushort_t* fw1b  = (ushort_t*)(wsb + HMB(19));
  ushort_t* fw2b  = (ushort_t*)(wsb + HMB(27));
  ushort_t* promptb = (ushort_t*)(wsb + HMB(35));
  float*    BQKV  = (float*)   (wsb + HMB(36));   // 18KB of 0.5 MiB unit
  float*    bcF   = (float*)   (wsb + HMB(36) + 32768);  // 2KB, same unit
  ushort_t* HQKVb = (ushort_t*)(wsb + HMB(37));   // 72 u, P1-P3 (37..109)
  float*    VNEW  = (float*)   (wsb + HMB(37));   // 48 u, P4-P10 (37..85)
  ushort_t* VNEWb = (ushort_t*)(wsb + HMB(85));   // 24 u, P4-P8 (85..109)
  ushort_t* VVTb  = (ushort_t*)(wsb + HMB(109));  // 24 u, P1-P2 (109..133)
  ushort_t* HN2b  = (ushort_t*)(wsb + HMB(109));  // 8 u, P5
  ushort_t* QCb   = (ushort_t*)(wsb + HMB(117));  // 8 u, P5-P6
  ushort_t* KVCb  = (ushort_t*)(wsb + HMB(125));  // 2 u, P5-P6
  ushort_t* COb   = (ushort_t*)(wsb + HMB(127));  // 8 u, P6-P7
  ushort_t* Vb    = (ushort_t*)(wsb + HMB(133));  // 24 u, P0-P1 (133..157)
  ushort_t* HRESb = (ushort_t*)(wsb + HMB(133));  // 8 u, P3-P4
  ushort_t* VRESb = (ushort_t*)(wsb + HMB(141));  // 24 u, P3-P4 (141..165)
  float*    H2    = (float*)   (wsb + HMB(143));  // 16 u, P7-P10 (143..159)
  ushort_t* HNb   = (ushort_t*)(wsb + HMB(157));  // 8 u, P0-P1 (157..165)
  ushort_t* VPb   = (ushort_t*)(wsb + HMB(159));  // 48 u, P8-P10 (159..207)
  ushort_t* VT    = (ushort_t*)(wsb + HMB(165));  // 32 u, P2-P3 (165..197)
  ushort_t* BIASCb= (ushort_t*)(wsb + HMB(197));  // 16 u, P0-P3 (197..213)
  float*    H1    = (float*)   (wsb + HMB(213));  // 16 u, P4-P7 (213..229)
  ushort_t* SCALb = (ushort_t*)(wsb + HMB(207));  // 16 u, P8-P9 (207..223)
  ushort_t* HH1b  = (ushort_t*)(wsb + HMB(223));  // 32 u, P9 (223..255)
  ushort_t* Wcb   = (ushort_t*)(wsb + HMB(255));  // 1 u, combine->P7 (255..256)

  // ---- P0: single fused launch (casts + caow^T + bc + biases + ln1) ----
  p0_fused<<<15828, 256, 0, stream>>>(
      Wq, Wqkvb, Wk, Wqkvb + (size_t)2048 * 512, Wv, Wqkvb + (size_t)4096 * 512,
      Wvv, Wvvb, Wo, Wob, Wvo, Wvob, caw, cawb,
      caow, caowTb,
      casw, caswb, flv, flvb, fw1, fw1b, fw2, fw2b, prompt, promptb, V, Vb,
      caob, casb, bcF,
      bq, bk, bv, BQKV, Db, rbf, mask, BIASCb, H, ln1g, ln1b, HNb);

  // ---- combine GEMM: Wc = casw @ caow  (bf16, 512x512x512) ----
  gemm_bf16_sm<<<dim3(4, 8), 256, 0, stream>>>(caswb, caowTb, nullptr, nullptr,
      nullptr, Wcb, nullptr, nullptr, 512, 512, 512, 16);

  // ---- P1: merged QKV projection + Vv projection ----
  gemm_bf16<<<dim3(36, 32), 256, 0, stream>>>(HNb, Wqkvb, BQKV, nullptr, nullptr, HQKVb, 4096, 4608, 512, 1 | 16);
  gemm_bf16<<<dim3(4, 96), 256, 0, stream>>>(Vb, Wvvb, nullptr, nullptr, nullptr, VVTb, 12288, 512, 512, 16);

  // ---- P2: V^T layout build ----
  vt_build<<<dim3(16, 4, 32), 256, 0, stream>>>(HQKVb, VVTb, VT);

  // ---- P3: fused self-attention ----
  attn_mfma<<<512, 256, 0, stream>>>(HQKVb, VT, BIASCb, HRESb, VRESb);

  // ---- P4: output projections + residuals ----
  gemm_bf16_sm<<<dim3(4, 64), 256, 0, stream>>>(HRESb, Wob, bo, H, H1, nullptr, nullptr, nullptr, 4096, 512, 512, 1 | 2 | 8);
  gemm_bf16<<<dim3(4, 96), 256, 0, stream>>>(VRESb, Wvob, nullptr, V, VNEW, VNEWb, 12288, 512, 512, 2 | 8 | 16);

  // ---- P5: cross-attention projections ----
  ln_kernel<<<4096, 256, 0, stream>>>(H1, ln2g, ln2b, HN2b, 512);
  gemm_bf16_sm<<<dim3(4, 64), 256, 0, stream>>>(HN2b, cawb, cab, nullptr, nullptr, QCb, nullptr, nullptr, 4096, 512, 512, 1 | 16);
  gemm_bf16_sm<<<dim3(8, 8), 256, 0, stream>>>(promptb, cawb + 262144, cab + 512, nullptr, nullptr, KVCb, nullptr, nullptr, 512, 1024, 512, 1 | 16);

  // ---- P6: cross-attention ----
  attn_cross_mfma<<<dim3(16, 32), 256, 0, stream>>>(QCb, KVCb, COb);

  // ---- P7: single fused output GEMM (caow∘casw pre-combined) ----
  gemm_bf16_sm<<<dim3(4, 64), 256, 0, stream>>>(COb, Wcb, bcF, H1, H2, nullptr, nullptr, nullptr, 4096, 512, 512, 1 | 2 | 8);

  // ---- P8: FFN inputs (flv GEMM, then fused ln3+vnorm) ----
  gemm_bf16<<<dim3(8, 96), 256, 0, stream>>>(VNEWb, flvb, nullptr, nullptr, nullptr, VPb, 12288, 1024, 512, 16);
  ln3_vnorm_fused<<<12288, 256, 0, stream>>>(H2, ln3g, ln3b, VPb, SCALb);

  // ---- P9: FFN + fused final combine ----
  gemm_bf16<<<dim3(16, 32), 256, 0, stream>>>(SCALb, fw1b, fb1, nullptr, nullptr, HH1b, 4096, 2048, 1024, 1 | 4 | 16);
  gemm_bf16_sm<<<dim3(8, 64), 256, 0, stream>>>(HH1b, fw2b, fb2, H2, out, nullptr, VPb, VNEW, 4096, 1024, 2048, 1 | 32);

  (void)in_sizes; (void)n_in; (void)out_size; (void)ws_size;
}

// Round 18
// 456.476 us; speedup vs baseline: 1.0327x; 1.0327x over previous
//
#include <hip/hip_runtime.h>
#include <cstdint>
#include <cstddef>

#define B_    4
#define N_    1024
#define P_    128
#define D_    512
#define NH_   8
#define QKVW  4608   // merged QKV row width

typedef unsigned short ushort_t;
typedef short short8 __attribute__((ext_vector_type(8)));
typedef float f32x4 __attribute__((ext_vector_type(4)));
typedef ushort_t ushort4_t __attribute__((ext_vector_type(4)));

__device__ inline ushort_t f2bf(float f) {
  union { float fp; unsigned int u; } v; v.fp = f;
  unsigned int r = v.u + 0x7fffu + ((v.u >> 16) & 1u);
  return (ushort_t)(r >> 16);
}
__device__ inline float bf2f(ushort_t u) {
  union { unsigned int i; float f; } v; v.i = ((unsigned int)u) << 16;
  return v.f;
}

__device__ __forceinline__ void gll16(const ushort_t* g, ushort_t* l) {
  __builtin_amdgcn_global_load_lds(
      (const __attribute__((address_space(1))) void*)g,
      (__attribute__((address_space(3))) void*)l, 16, 0, 0);
}

// ---------------------------------------------------------------------------
// P0 mega-kernel: fused casts + bias-merge + combined-bias + ln1
// ---------------------------------------------------------------------------
__device__ inline void cast8(const float* __restrict__ s, ushort_t* __restrict__ d,
                             unsigned i) {
  const float* sp = s + (size_t)i * 8;
  short8 o;
#pragma unroll
  for (int j = 0; j < 8; ++j) o[j] = (short)f2bf(sp[j]);
  *(short8*)(d + (size_t)i * 8) = o;
}

__global__ __launch_bounds__(256) void p0_fused(
    const float* s0, ushort_t* d0,  const float* s1, ushort_t* d1,
    const float* s2, ushort_t* d2,  const float* s3, ushort_t* d3,
    const float* s4, ushort_t* d4,  const float* s5, ushort_t* d5,
    const float* s6, ushort_t* d6,  const float* s7, ushort_t* d7,
    const float* s8, ushort_t* d8,  const float* s9, ushort_t* d9,
    const float* s10, ushort_t* d10, const float* s11, ushort_t* d11,
    const float* s12, ushort_t* d12, const float* s13, ushort_t* d13,
    const float* bq, const float* bk, const float* bv, float* bqkv,
    const float* Db, const float* rbf, const int* mask, ushort_t* biasc,
    const float* Hx, const float* g1, const float* b1, ushort_t* hn)
{
  const int blk = blockIdx.x;
  const int tid = threadIdx.x;

  if (blk < 7680) {
    unsigned i = blk * 256 + tid;
#define SEG(s, d, n8) if (i < (n8)) { cast8(s, d, i); return; } i -= (n8);
    SEG(s0, d0, 131072u)   // Wq
    SEG(s1, d1, 131072u)   // Wk
    SEG(s2, d2, 32768u)    // Wv
    SEG(s3, d3, 32768u)    // Wvv
    SEG(s4, d4, 32768u)    // Wo
    SEG(s5, d5, 32768u)    // Wvo
    SEG(s6, d6, 98304u)    // caw
    SEG(s7, d7, 32768u)    // caow
    SEG(s8, d8, 32768u)    // casw
    SEG(s9, d9, 65536u)    // flv
    SEG(s10, d10, 262144u) // fw1
    SEG(s11, d11, 262144u) // fw2
    SEG(s12, d12, 32768u)  // prompt
    SEG(s13, d13, 786432u) // V
#undef SEG
    return;
  }
  if (blk < 7698) {
    int i = (blk - 7680) * 256 + tid;
    if (i < 4608)
      bqkv[i] = (i < 2048) ? bq[i] : (i < 4096) ? bk[i - 2048] : bv[i - 4096];
    return;
  }
  if (blk < 11794) {
    size_t i = (size_t)(blk - 7698) * 256 + tid;
    size_t e = i * 4;
    int b  = (int)(e >> 20);
    int m0 = (int)(e & 1023);
    float4 r = *(const float4*)(rbf + e);
    float4 d = *(const float4*)(Db + e);
    const int* mp = mask + b * 1024 + m0;
    ushort4_t o;
    o.x = f2bf(mp[0] ? r.x + d.x : -1e30f);
    o.y = f2bf(mp[1] ? r.y + d.y : -1e30f);
    o.z = f2bf(mp[2] ? r.z + d.z : -1e30f);
    o.w = f2bf(mp[3] ? r.w + d.w : -1e30f);
    *(ushort4_t*)(biasc + e) = o;
    return;
  }
  {
    int row = blk - 11794;
    const float* xr = Hx + (size_t)row * D_;
    float a = xr[tid], c = xr[tid + 256];
    float s = a + c, sq = a * a + c * c;
#pragma unroll
    for (int off = 32; off >= 1; off >>= 1) {
      s  += __shfl_xor(s, off);
      sq += __shfl_xor(sq, off);
    }
    __shared__ float red[8];
    int w = tid >> 6, lane = tid & 63;
    if (lane == 0) { red[w] = s; red[4 + w] = sq; }
    __syncthreads();
    float st  = red[0] + red[1] + red[2] + red[3];
    float sqt = red[4] + red[5] + red[6] + red[7];
    float mean = st * (1.0f / D_);
    float var  = sqt * (1.0f / D_) - mean * mean;
    float inv  = rsqrtf(var + 1e-5f);
    hn[(size_t)row * 512 + tid]       = f2bf((a - mean) * inv * g1[tid] + b1[tid]);
    hn[(size_t)row * 512 + tid + 256] = f2bf((c - mean) * inv * g1[tid + 256] + b1[tid + 256]);
  }
}

// ---------------------------------------------------------------------------
// LayerNorm (fp32 in, bf16 out)
// ---------------------------------------------------------------------------
__global__ __launch_bounds__(256) void ln_kernel(
    const float* __restrict__ x, const float* __restrict__ g,
    const float* __restrict__ bb, ushort_t* __restrict__ y, int ostride)
{
  int row = blockIdx.x;
  int t = threadIdx.x;
  const float* xr = x + (size_t)row * D_;
  float a = xr[t], c = xr[t + 256];
  float s = a + c, sq = a * a + c * c;
#pragma unroll
  for (int off = 32; off >= 1; off >>= 1) {
    s  += __shfl_xor(s, off);
    sq += __shfl_xor(sq, off);
  }
  __shared__ float red[8];
  int w = t >> 6, lane = t & 63;
  if (lane == 0) { red[w] = s; red[4 + w] = sq; }
  __syncthreads();
  float st  = red[0] + red[1] + red[2] + red[3];
  float sqt = red[4] + red[5] + red[6] + red[7];
  float mean = st * (1.0f / D_);
  float var  = sqt * (1.0f / D_) - mean * mean;
  float inv  = rsqrtf(var + 1e-5f);
  y[(size_t)row * ostride + t]       = f2bf((a - mean) * inv * g[t] + bb[t]);
  y[(size_t)row * ostride + t + 256] = f2bf((c - mean) * inv * g[t + 256] + bb[t + 256]);
}

// ---------------------------------------------------------------------------
// Fused ln3 + vnorm: blocks [0,4096) = ln3 rows (H2 -> SCALb cols 0..511);
// blocks [4096,12288) = vnorm (VPb -> SCALb cols 512..1023).
// ---------------------------------------------------------------------------
__global__ __launch_bounds__(256) void ln3_vnorm_fused(
    const float* __restrict__ x, const float* __restrict__ g,
    const float* __restrict__ bb, const ushort_t* __restrict__ Vp,
    ushort_t* __restrict__ scal)
{
  const int blk = blockIdx.x;
  const int t = threadIdx.x;
  if (blk < 4096) {
    int row = blk;
    const float* xr = x + (size_t)row * D_;
    float a = xr[t], c = xr[t + 256];
    float s = a + c, sq = a * a + c * c;
#pragma unroll
    for (int off = 32; off >= 1; off >>= 1) {
      s  += __shfl_xor(s, off);
      sq += __shfl_xor(sq, off);
    }
    __shared__ float red[8];
    int w = t >> 6, lane = t & 63;
    if (lane == 0) { red[w] = s; red[4 + w] = sq; }
    __syncthreads();
    float st  = red[0] + red[1] + red[2] + red[3];
    float sqt = red[4] + red[5] + red[6] + red[7];
    float mean = st * (1.0f / D_);
    float var  = sqt * (1.0f / D_) - mean * mean;
    float inv  = rsqrtf(var + 1e-5f);
    scal[(size_t)row * 1024 + t]       = f2bf((a - mean) * inv * g[t] + bb[t]);
    scal[(size_t)row * 1024 + t + 256] = f2bf((c - mean) * inv * g[t + 256] + bb[t + 256]);
    return;
  }
  size_t i = (size_t)(blk - 4096) * 256 + t;
  size_t bn = i >> 9; int d = (int)(i & 511);
  size_t base = bn * 3 * 1024 + d;
  float a = bf2f(Vp[base]);
  float b = bf2f(Vp[base + 1024]);
  float c = bf2f(Vp[base + 2048]);
  scal[bn * 1024 + 512 + d] = f2bf(sqrtf(a * a + b * b + c * c));
}

// ---------------------------------------------------------------------------
// bf16 MFMA GEMM, 128x128 tile (gll16 staging + swizzle + XCD remap)
// flags: 1=bias 2=res 4=silu 8=write fp32 16=write bf16
// ---------------------------------------------------------------------------
__global__ __launch_bounds__(256) void gemm_bf16(
    const ushort_t* __restrict__ A, const ushort_t* __restrict__ W,
    const float* __restrict__ bias, const float* __restrict__ res,
    float* __restrict__ Cf, ushort_t* __restrict__ Cb,
    int M, int N, int K, int flags)
{
  __shared__ __align__(16) ushort_t Al[128 * 32];
  __shared__ __align__(16) ushort_t Wl[128 * 32];
  const int t = threadIdx.x;
  const int wv = t >> 6, lane = t & 63, lr = lane & 15, lk = lane >> 4;
  const int wr = wv >> 1, wc = wv & 1;

  const int gx = gridDim.x;
  const int lid = blockIdx.y * gx + blockIdx.x;
  const int cpx = (gx * gridDim.y) >> 3;
  const int nlid = (lid & 7) * cpx + (lid >> 3);
  const size_t row0 = (size_t)(nlid / gx) * 128;
  const size_t col0 = (size_t)(nlid % gx) * 128;

  const int srow = 32 * wv + (lane >> 2);
  const int scol = (((lane & 3) ^ ((lane >> 3) & 3))) * 8;
  const ushort_t* ApG = A + (row0 + srow) * (size_t)K + scol;
  const ushort_t* WpG = W + (col0 + srow) * (size_t)K + scol;
  ushort_t* AlD = Al + (size_t)(32 * wv) * 32;
  ushort_t* WlD = Wl + (size_t)(32 * wv) * 32;
  const size_t K16 = (size_t)16 * K;

  f32x4 acc[4][4];
#pragma unroll
  for (int i = 0; i < 4; ++i)
#pragma unroll
    for (int j = 0; j < 4; ++j) acc[i][j] = f32x4{0.f, 0.f, 0.f, 0.f};

  const int sx = (lr >> 1) & 3;

  for (int k0 = 0; k0 < K; k0 += 32) {
    __syncthreads();
    gll16(ApG + k0,       AlD);
    gll16(ApG + k0 + K16, AlD + 512);
    gll16(WpG + k0,       WlD);
    gll16(WpG + k0 + K16, WlD + 512);
    __syncthreads();
    short8 af[4], bf[4];
#pragma unroll
    for (int i = 0; i < 4; ++i)
      af[i] = *(const short8*)&Al[(wr * 64 + i * 16 + lr) * 32 + ((lk ^ sx) << 3)];
#pragma unroll
    for (int j = 0; j < 4; ++j)
      bf[j] = *(const short8*)&Wl[(wc * 64 + j * 16 + lr) * 32 + ((lk ^ sx) << 3)];
#pragma unroll
    for (int i = 0; i < 4; ++i)
#pragma unroll
      for (int j = 0; j < 4; ++j)
        acc[i][j] = __builtin_amdgcn_mfma_f32_16x16x32_bf16(af[i], bf[j], acc[i][j], 0, 0, 0);
  }

  const int orow = wr * 64 + lk * 4, ocol = wc * 64 + lr;
#pragma unroll
  for (int i = 0; i < 4; ++i) {
#pragma unroll
    for (int j = 0; j < 4; ++j) {
      size_t colb = col0 + ocol + j * 16;
      float bv = (flags & 1) ? bias[colb] : 0.f;
#pragma unroll
      for (int r = 0; r < 4; ++r) {
        size_t rowg = row0 + orow + i * 16 + r;
        float v = acc[i][j][r] + bv;
        if (flags & 4) v = v / (1.f + __expf(-v));
        if (flags & 2) v += res[rowg * N + colb];
        if (flags & 8)  Cf[rowg * N + colb] = v;
        if (flags & 16) Cb[rowg * N + colb] = f2bf(v);
      }
    }
  }
}

// ---------------------------------------------------------------------------
// Small-M GEMM variant: BM=64 x BN=128.  flags 32 = fused "final" epilogue.
// ---------------------------------------------------------------------------
__global__ __launch_bounds__(256) void gemm_bf16_sm(
    const ushort_t* __restrict__ A, const ushort_t* __restrict__ W,
    const float* __restrict__ bias, const float* __restrict__ res,
    float* __restrict__ Cf, ushort_t* __restrict__ Cb,
    const ushort_t* __restrict__ Vp, const float* __restrict__ Vnw,
    int M, int N, int K, int flags)
{
  __shared__ __align__(16) ushort_t Al[64 * 32];
  __shared__ __align__(16) ushort_t Wl[128 * 32];
  const int t = threadIdx.x;
  const int wv = t >> 6, lane = t & 63, lr = lane & 15, lk = lane >> 4;
  const int wr = wv >> 1, wc = wv & 1;

  const int gx = gridDim.x;
  const int lid = blockIdx.y * gx + blockIdx.x;
  const int cpx = (gx * gridDim.y) >> 3;
  const int nlid = (lid & 7) * cpx + (lid >> 3);
  const size_t row0 = (size_t)(nlid / gx) * 64;
  const size_t col0 = (size_t)(nlid % gx) * 128;

  const int scol = (((lane & 3) ^ ((lane >> 3) & 3))) * 8;
  const int srowA = 16 * wv + (lane >> 2);
  const int srowW = 32 * wv + (lane >> 2);
  const ushort_t* ApG = A + (row0 + srowA) * (size_t)K + scol;
  const ushort_t* WpG = W + (col0 + srowW) * (size_t)K + scol;
  ushort_t* AlD = Al + (size_t)(16 * wv) * 32;
  ushort_t* WlD = Wl + (size_t)(32 * wv) * 32;
  const size_t K16 = (size_t)16 * K;

  f32x4 acc[2][4];
#pragma unroll
  for (int i = 0; i < 2; ++i)
#pragma unroll
    for (int j = 0; j < 4; ++j) acc[i][j] = f32x4{0.f, 0.f, 0.f, 0.f};

  const int sx = (lr >> 1) & 3;

  for (int k0 = 0; k0 < K; k0 += 32) {
    __syncthreads();
    gll16(ApG + k0,       AlD);
    gll16(WpG + k0,       WlD);
    gll16(WpG + k0 + K16, WlD + 512);
    __syncthreads();
    short8 af[2], bf[4];
#pragma unroll
    for (int i = 0; i < 2; ++i)
      af[i] = *(const short8*)&Al[(wr * 32 + i * 16 + lr) * 32 + ((lk ^ sx) << 3)];
#pragma unroll
    for (int j = 0; j < 4; ++j)
      bf[j] = *(const short8*)&Wl[(wc * 64 + j * 16 + lr) * 32 + ((lk ^ sx) << 3)];
#pragma unroll
    for (int i = 0; i < 2; ++i)
#pragma unroll
      for (int j = 0; j < 4; ++j)
        acc[i][j] = __builtin_amdgcn_mfma_f32_16x16x32_bf16(af[i], bf[j], acc[i][j], 0, 0, 0);
  }

  const int orow = wr * 32 + lk * 4, ocol = wc * 64 + lr;
#pragma unroll
  for (int i = 0; i < 2; ++i) {
#pragma unroll
    for (int j = 0; j < 4; ++j) {
      size_t colb = col0 + ocol + j * 16;
      float bv = (flags & 1) ? bias[colb] : 0.f;
#pragma unroll
      for (int r = 0; r < 4; ++r) {
        size_t rowg = row0 + orow + i * 16 + r;
        float v = acc[i][j][r] + bv;
        if (flags & 4) v = v / (1.f + __expf(-v));
        if (flags & 32) {
          if (colb < 512) {
            Cf[rowg * 512 + colb] = v + res[rowg * 512 + colb];
          } else {
            int dd = (int)colb - 512;
            float* outV = Cf + (size_t)4096 * 512;
#pragma unroll
            for (int c = 0; c < 3; ++c) {
              size_t vi = (rowg * 3 + c) * 512 + dd;
              outV[vi] = v * bf2f(Vp[(rowg * 3 + c) * 1024 + 512 + dd]) + Vnw[vi];
            }
          }
          continue;
        }
        if (flags & 2) v += res[rowg * N + colb];
        if (flags & 8)  Cf[rowg * N + colb] = v;
        if (flags & 16) Cb[rowg * N + colb] = f2bf(v);
      }
    }
  }
}

// ---------------------------------------------------------------------------
// Build VT[b][h][dcat(256)][n(1024)] bf16.
// ---------------------------------------------------------------------------
__global__ __launch_bounds__(256) void vt_build(
    const ushort_t* __restrict__ QKVb, const ushort_t* __restrict__ VVTb,
    ushort_t* __restrict__ VT)
{
  const int bh = blockIdx.z, b = bh >> 3, h = bh & 7;
  const int n0 = blockIdx.x * 64, dt = blockIdx.y;
  __shared__ __align__(16) ushort_t tile[64][72];
  const int t = threadIdx.x;
  {
    int r = t >> 2, c0 = (t & 3) * 16;
    const ushort_t* src = (dt == 0)
      ? QKVb + ((size_t)(b * 1024 + n0 + r)) * QKVW + 4096 + h * 64 + c0
      : VVTb + (((size_t)(b * 1024 + n0 + r)) * 3 + (dt - 1)) * 512 + h * 64 + c0;
    *(short8*)&tile[r][c0]     = *(const short8*)src;
    *(short8*)&tile[r][c0 + 8] = *(const short8*)(src + 8);
  }
  __syncthreads();
  {
    int d = t >> 2, nc = (t & 3) * 16;
    short8 o0, o1;
#pragma unroll
    for (int i = 0; i < 8; ++i) { o0[i] = tile[nc + i][d]; o1[i] = tile[nc + 8 + i][d]; }
    ushort_t* dst = VT + ((size_t)bh * 256 + dt * 64 + d) * 1024 + n0 + nc;
    *(short8*)dst = o0;
    *(short8*)(dst + 8) = o1;
  }
}

// ---------------------------------------------------------------------------
// Fused self-attention — r13 known-good body (KVBLK=32, pitch-268 K tile).
// ---------------------------------------------------------------------------
__global__ __launch_bounds__(256) void attn_mfma(
    const ushort_t* __restrict__ QKg, const ushort_t* __restrict__ VTg,
    const ushort_t* __restrict__ biasb,
    ushort_t* __restrict__ HRESb, ushort_t* __restrict__ VRESb)
{
  const int blk = blockIdx.x;
  const int bi = blk >> 3;
  const int bh = (blk & 7) * 4 + (bi >> 4), b = bh >> 3, h = bh & 7;
  const int q0 = (bi & 15) * 64;
  const int t = threadIdx.x, w = t >> 6, lane = t & 63, lr = lane & 15, lk = lane >> 4;

  __shared__ __align__(16) ushort_t Kl[32][268];
  __shared__ __align__(16) ushort_t Vl[256][40];
  __shared__ __align__(16) ushort_t Pl[4][16][40];

  short8 qf[8];
  {
    const ushort_t* qb = QKg + ((size_t)(b * 1024 + q0 + w * 16 + lr)) * QKVW + h * 256;
#pragma unroll
    for (int s = 0; s < 8; ++s) qf[s] = *(const short8*)(qb + s * 32 + lk * 8);
  }
  f32x4 o[16];
#pragma unroll
  for (int i = 0; i < 16; ++i) o[i] = f32x4{0.f, 0.f, 0.f, 0.f};
  float mrow[4] = {-1e30f, -1e30f, -1e30f, -1e30f};
  float lsum[4] = {0.f, 0.f, 0.f, 0.f};
  const int qrow = q0 + w * 16 + lk * 4;

  const int krow = t >> 3, kc = (t & 7) * 32;
  const ushort_t* ksrc = QKg + ((size_t)(b * 1024 + krow)) * QKVW + 2048 + h * 256 + kc;
  const ushort_t* vsrc = VTg + ((size_t)bh * 256 + t) * 1024;
  const int vrot = (t >> 3) & 3;

  for (int k0 = 0; k0 < 1024; k0 += 32) {
    __syncthreads();
    {
      const ushort_t* ks = ksrc + (size_t)k0 * QKVW;
#pragma unroll
      for (int c = 0; c < 4; ++c)
        *(short8*)&Kl[krow][kc + c * 8] = *(const short8*)(ks + c * 8);
#pragma unroll
      for (int c = 0; c < 4; ++c) {
        int cc = (c + vrot) & 3;
        *(short8*)&Vl[t][cc * 8] = *(const short8*)(vsrc + k0 + cc * 8);
      }
    }
    __syncthreads();

    f32x4 s2[2];
    s2[0] = f32x4{0.f, 0.f, 0.f, 0.f};
    s2[1] = f32x4{0.f, 0.f, 0.f, 0.f};
    __builtin_amdgcn_s_setprio(1);
#pragma unroll
    for (int ks = 0; ks < 8; ++ks) {
#pragma unroll
      for (int j = 0; j < 2; ++j) {
        short8 kf = *(const short8*)&Kl[j * 16 + lr][ks * 32 + lk * 8];
        s2[j] = __builtin_amdgcn_mfma_f32_16x16x32_bf16(qf[ks], kf, s2[j], 0, 0, 0);
      }
    }
    __builtin_amdgcn_s_setprio(0);

    float sv[2][4];
    const ushort_t* bp = biasb + ((size_t)b << 20) + (size_t)qrow * 1024 + k0 + lr;
#pragma unroll
    for (int r = 0; r < 4; ++r) {
      sv[0][r] = s2[0][r] * 0.0625f + bf2f(bp[r * 1024]);
      sv[1][r] = s2[1][r] * 0.0625f + bf2f(bp[r * 1024 + 16]);
    }
    float pm[4], need = -1e30f;
#pragma unroll
    for (int r = 0; r < 4; ++r) {
      float m2 = fmaxf(sv[0][r], sv[1][r]);
      m2 = fmaxf(m2, __shfl_xor(m2, 1));
      m2 = fmaxf(m2, __shfl_xor(m2, 2));
      m2 = fmaxf(m2, __shfl_xor(m2, 4));
      m2 = fmaxf(m2, __shfl_xor(m2, 8));
      pm[r] = m2;
      need = fmaxf(need, m2 - mrow[r]);
    }
    if (!__all(need <= 8.f)) {
#pragma unroll
      for (int r = 0; r < 4; ++r) {
        float mn = fmaxf(mrow[r], pm[r]);
        float al = __expf(mrow[r] - mn);
        mrow[r] = mn;
        lsum[r] *= al;
#pragma unroll
        for (int d = 0; d < 16; ++d) o[d][r] *= al;
      }
    }
#pragma unroll
    for (int r = 0; r < 4; ++r) {
      float p0 = __expf(sv[0][r] - mrow[r]);
      float p1 = __expf(sv[1][r] - mrow[r]);
      float rs = p0 + p1;
      rs += __shfl_xor(rs, 1); rs += __shfl_xor(rs, 2);
      rs += __shfl_xor(rs, 4); rs += __shfl_xor(rs, 8);
      lsum[r] += rs;
      Pl[w][lk * 4 + r][lr]      = f2bf(p0);
      Pl[w][lk * 4 + r][16 + lr] = f2bf(p1);
    }
    short8 pf = *(const short8*)&Pl[w][lr][lk * 8];
    __builtin_amdgcn_s_setprio(1);
#pragma unroll
    for (int d = 0; d < 16; ++d) {
      short8 vf = *(const short8*)&Vl[d * 16 + lr][lk * 8];
      o[d] = __builtin_amdgcn_mfma_f32_16x16x32_bf16(pf, vf, o[d], 0, 0, 0);
    }
    __builtin_amdgcn_s_setprio(0);
  }

  float inv[4];
#pragma unroll
  for (int r = 0; r < 4; ++r) inv[r] = 1.f / lsum[r];
#pragma unroll
  for (int d = 0; d < 16; ++d) {
    int dcat = d * 16 + lr;
#pragma unroll
    for (int r = 0; r < 4; ++r) {
      float v = o[d][r] * inv[r];
      int n = qrow + r;
      if (dcat < 64)
        HRESb[((size_t)b * 1024 + n) * 512 + h * 64 + dcat] = f2bf(v);
      else {
        int c = (dcat - 64) >> 6, jj = (dcat - 64) & 63;
        VRESb[(((size_t)b * 1024 + n) * 3 + c) * 512 + h * 64 + jj] = f2bf(v);
      }
    }
  }
}

// ---------------------------------------------------------------------------
// Cross-attention, bf16 MFMA.
// ---------------------------------------------------------------------------
__global__ __launch_bounds__(256) void attn_cross_mfma(
    const ushort_t* __restrict__ Qb, const ushort_t* __restrict__ KVb,
    ushort_t* __restrict__ COb)
{
  const int bh = blockIdx.y, b = bh >> 3, h = bh & 7;
  const int q0 = blockIdx.x * 64;
  const int t = threadIdx.x, w = t >> 6, lane = t & 63, lr = lane & 15, lk = lane >> 4;

  __shared__ __align__(16) ushort_t Kl[128][72];
  __shared__ __align__(16) ushort_t Vt[64][136];
  __shared__ __align__(16) ushort_t Pl[4][16][136];

  {
    int p = t >> 1, c0 = (t & 1) * 32;
    const ushort_t* kp = KVb + ((size_t)b * 128 + p) * 1024 + h * 64 + c0;
#pragma unroll
    for (int i = 0; i < 4; ++i) {
      short8 kv = *(const short8*)(kp + i * 8);
      *(short8*)&Kl[p][c0 + i * 8] = kv;
      short8 vv = *(const short8*)(kp + 512 + i * 8);
#pragma unroll
      for (int jj = 0; jj < 8; ++jj) Vt[c0 + i * 8 + jj][p] = (ushort_t)vv[jj];
    }
  }
  __syncthreads();

  short8 qf[2];
  {
    const ushort_t* qp = Qb + ((size_t)b * 1024 + q0 + w * 16 + lr) * 512 + h * 64;
    qf[0] = *(const short8*)(qp + lk * 8);
    qf[1] = *(const short8*)(qp + 32 + lk * 8);
  }

  f32x4 s[8];
#pragma unroll
  for (int j = 0; j < 8; ++j) s[j] = f32x4{0.f, 0.f, 0.f, 0.f};
#pragma unroll
  for (int ks = 0; ks < 2; ++ks)
#pragma unroll
    for (int j = 0; j < 8; ++j) {
      short8 kf = *(const short8*)&Kl[j * 16 + lr][ks * 32 + lk * 8];
      s[j] = __builtin_amdgcn_mfma_f32_16x16x32_bf16(qf[ks], kf, s[j], 0, 0, 0);
    }

  float linv[4];
#pragma unroll
  for (int r = 0; r < 4; ++r) {
    float sc[8];
#pragma unroll
    for (int j = 0; j < 8; ++j) sc[j] = s[j][r] * 0.125f;
    float mx = sc[0];
#pragma unroll
    for (int j = 1; j < 8; ++j) mx = fmaxf(mx, sc[j]);
    mx = fmaxf(mx, __shfl_xor(mx, 1));
    mx = fmaxf(mx, __shfl_xor(mx, 2));
    mx = fmaxf(mx, __shfl_xor(mx, 4));
    mx = fmaxf(mx, __shfl_xor(mx, 8));
    float rs = 0.f;
#pragma unroll
    for (int j = 0; j < 8; ++j) {
      float p = __expf(sc[j] - mx);
      rs += p;
      Pl[w][lk * 4 + r][j * 16 + lr] = f2bf(p);
    }
    rs += __shfl_xor(rs, 1); rs += __shfl_xor(rs, 2);
    rs += __shfl_xor(rs, 4); rs += __shfl_xor(rs, 8);
    linv[r] = 1.f / rs;
  }
  __syncthreads();

  f32x4 o[4];
#pragma unroll
  for (int d = 0; d < 4; ++d) o[d] = f32x4{0.f, 0.f, 0.f, 0.f};
#pragma unroll
  for (int ks = 0; ks < 4; ++ks) {
    short8 pf = *(const short8*)&Pl[w][lr][ks * 32 + lk * 8];
#pragma unroll
    for (int d = 0; d < 4; ++d) {
      short8 vf = *(const short8*)&Vt[d * 16 + lr][ks * 32 + lk * 8];
      o[d] = __builtin_amdgcn_mfma_f32_16x16x32_bf16(pf, vf, o[d], 0, 0, 0);
    }
  }

#pragma unroll
  for (int d = 0; d < 4; ++d)
#pragma unroll
    for (int r = 0; r < 4; ++r) {
      int n = q0 + w * 16 + lk * 4 + r;
      COb[((size_t)b * 1024 + n) * 512 + h * 64 + d * 16 + lr] = f2bf(o[d][r] * linv[r]);
    }
}

// ---------------------------------------------------------------------------
extern "C" void kernel_launch(void* const* d_in, const int* in_sizes, int n_in,
                              void* d_out, int out_size, void* d_ws, size_t ws_size,
                              hipStream_t stream)
{
  const float* H      = (const float*)d_in[0];
  const float* V      = (const float*)d_in[1];
  const float* Db     = (const float*)d_in[2];
  const float* rbf    = (const float*)d_in[3];
  const float* prompt = (const float*)d_in[4];
  const float* Wq  = (const float*)d_in[5];
  const float* bq  = (const float*)d_in[6];
  const float* Wk  = (const float*)d_in[7];
  const float* bk  = (const float*)d_in[8];
  const float* Wv  = (const float*)d_in[9];
  const float* bv  = (const float*)d_in[10];
  const float* Wvv = (const float*)d_in[11];
  const float* Wo  = (const float*)d_in[12];
  const float* bo  = (const float*)d_in[13];
  const float* Wvo = (const float*)d_in[14];
  const float* ln1g = (const float*)d_in[15];
  const float* ln1b = (const float*)d_in[16];
  const float* caw  = (const float*)d_in[17];
  const float* cab  = (const float*)d_in[18];
  const float* caow = (const float*)d_in[19];
  const float* caob = (const float*)d_in[20];
  const float* casw = (const float*)d_in[21];
  const float* casb = (const float*)d_in[22];
  const float* ln2g = (const float*)d_in[23];
  const float* ln2b = (const float*)d_in[24];
  const float* flv  = (const float*)d_in[25];
  const float* fw1  = (const float*)d_in[26];
  const float* fb1  = (const float*)d_in[27];
  const float* fw2  = (const float*)d_in[28];
  const float* fb2  = (const float*)d_in[29];
  const float* ln3g = (const float*)d_in[30];
  const float* ln3b = (const float*)d_in[31];
  const int*   mask = (const int*)d_in[32];

  char* wsb = (char*)d_ws;
  float* out = (float*)d_out;

  // offsets in 0.5 MiB units; lifetimes audited (r8 map); max 255 u
#define HMB(x) ((size_t)(x) << 19)
  ushort_t* Wqkvb = (ushort_t*)(wsb + HMB(0));    // 9 u
  ushort_t* Wvvb  = (ushort_t*)(wsb + HMB(9));
  ushort_t* Wob   = (ushort_t*)(wsb + HMB(10));
  ushort_t* Wvob  = (ushort_t*)(wsb + HMB(11));
  ushort_t* cawb  = (ushort_t*)(wsb + HMB(12));
  ushort_t* caowb = (ushort_t*)(wsb + HMB(15));
  ushort_t* caswb = (ushort_t*)(wsb + HMB(16));
  ushort_t* flvb  = (ushort_t*)(wsb + HMB(17));
  ushort_t* fw1b  = (ushort_t*)(wsb + HMB(19));
  ushort_t* fw2b  = (ushort_t*)(wsb + HMB(27));
  ushort_t* promptb = (ushort_t*)(wsb + HMB(35));
  float*    BQKV  = (float*)   (wsb + HMB(36));   // 1 u
  ushort_t* HQKVb = (ushort_t*)(wsb + HMB(37));   // 72 u, P1-P3 (37..109)
  float*    VNEW  = (float*)   (wsb + HMB(37));   // 48 u, P4-P10 (37..85)
  ushort_t* VNEWb = (ushort_t*)(wsb + HMB(85));   // 24 u, P4-P8 (85..109)
  ushort_t* VVTb  = (ushort_t*)(wsb + HMB(109));  // 24 u, P1-P2 (109..133)
  ushort_t* HN2b  = (ushort_t*)(wsb + HMB(109));  // 8 u, P5
  ushort_t* QCb   = (ushort_t*)(wsb + HMB(117));  // 8 u, P5-P6
  ushort_t* KVCb  = (ushort_t*)(wsb + HMB(125));  // 2 u, P5-P6
  ushort_t* COb   = (ushort_t*)(wsb + HMB(127));  // 8 u, P6-P7
  ushort_t* Vb    = (ushort_t*)(wsb + HMB(133));  // 24 u, P0-P1 (133..157)
  ushort_t* HRESb = (ushort_t*)(wsb + HMB(133));  // 8 u, P3-P4
  ushort_t* CO2b  = (ushort_t*)(wsb + HMB(135));  // 8 u, P7 (135..143)
  ushort_t* VRESb = (ushort_t*)(wsb + HMB(141));  // 24 u, P3-P4 (141..165)
  float*    H2    = (float*)   (wsb + HMB(143));  // 16 u, P7-P10 (143..159)
  ushort_t* HNb   = (ushort_t*)(wsb + HMB(157));  // 8 u, P0-P1 (157..165)
  ushort_t* VPb   = (ushort_t*)(wsb + HMB(159));  // 48 u, P8-P10 (159..207)
  ushort_t* VT    = (ushort_t*)(wsb + HMB(165));  // 32 u, P2-P3 (165..197)
  ushort_t* BIASCb= (ushort_t*)(wsb + HMB(197));  // 16 u, P0-P3 (197..213)
  float*    H1    = (float*)   (wsb + HMB(213));  // 16 u, P4-P7 (213..229)
  ushort_t* SCALb = (ushort_t*)(wsb + HMB(207));  // 16 u, P8-P9 (207..223)
  ushort_t* HH1b  = (ushort_t*)(wsb + HMB(223));  // 32 u, P9 (223..255)

  // ---- P0: single fused launch ----
  p0_fused<<<15890, 256, 0, stream>>>(
      Wq, Wqkvb, Wk, Wqkvb + (size_t)2048 * 512, Wv, Wqkvb + (size_t)4096 * 512,
      Wvv, Wvvb, Wo, Wob, Wvo, Wvob, caw, cawb, caow, caowb, casw, caswb,
      flv, flvb, fw1, fw1b, fw2, fw2b, prompt, promptb, V, Vb,
      bq, bk, bv, BQKV, Db, rbf, mask, BIASCb, H, ln1g, ln1b, HNb);

  // ---- P1: merged QKV projection + Vv projection ----
  gemm_bf16<<<dim3(36, 32), 256, 0, stream>>>(HNb, Wqkvb, BQKV, nullptr, nullptr, HQKVb, 4096, 4608, 512, 1 | 16);
  gemm_bf16<<<dim3(4, 96), 256, 0, stream>>>(Vb, Wvvb, nullptr, nullptr, nullptr, VVTb, 12288, 512, 512, 16);

  // ---- P2: V^T layout build ----
  vt_build<<<dim3(16, 4, 32), 256, 0, stream>>>(HQKVb, VVTb, VT);

  // ---- P3: fused self-attention ----
  attn_mfma<<<512, 256, 0, stream>>>(HQKVb, VT, BIASCb, HRESb, VRESb);

  // ---- P4: output projections + residuals ----
  gemm_bf16_sm<<<dim3(4, 64), 256, 0, stream>>>(HRESb, Wob, bo, H, H1, nullptr, nullptr, nullptr, 4096, 512, 512, 1 | 2 | 8);
  gemm_bf16<<<dim3(4, 96), 256, 0, stream>>>(VRESb, Wvob, nullptr, V, VNEW, VNEWb, 12288, 512, 512, 2 | 8 | 16);

  // ---- P5: cross-attention projections ----
  ln_kernel<<<4096, 256, 0, stream>>>(H1, ln2g, ln2b, HN2b, 512);
  gemm_bf16_sm<<<dim3(4, 64), 256, 0, stream>>>(HN2b, cawb, cab, nullptr, nullptr, QCb, nullptr, nullptr, 4096, 512, 512, 1 | 16);
  gemm_bf16_sm<<<dim3(8, 8), 256, 0, stream>>>(promptb, cawb + 262144, cab + 512, nullptr, nullptr, KVCb, nullptr, nullptr, 512, 1024, 512, 1 | 16);

  // ---- P6: cross-attention ----
  attn_cross_mfma<<<dim3(16, 32), 256, 0, stream>>>(QCb, KVCb, COb);

  // ---- P7: cross-attention output path ----
  gemm_bf16_sm<<<dim3(4, 64), 256, 0, stream>>>(COb, caowb, caob, nullptr, nullptr, CO2b, nullptr, nullptr, 4096, 512, 512, 1 | 16);
  gemm_bf16_sm<<<dim3(4, 64), 256, 0, stream>>>(CO2b, caswb, casb, H1, H2, nullptr, nullptr, nullptr, 4096, 512, 512, 1 | 2 | 8);

  // ---- P8: FFN inputs (flv GEMM, then fused ln3+vnorm) ----
  gemm_bf16<<<dim3(8, 96), 256, 0, stream>>>(VNEWb, flvb, nullptr, nullptr, nullptr, VPb, 12288, 1024, 512, 16);
  ln3_vnorm_fused<<<12288, 256, 0, stream>>>(H2, ln3g, ln3b, VPb, SCALb);

  // ---- P9: FFN + fused final combine ----
  gemm_bf16<<<dim3(16, 32), 256, 0, stream>>>(SCALb, fw1b, fb1, nullptr, nullptr, HH1b, 4096, 2048, 1024, 1 | 4 | 16);
  gemm_bf16_sm<<<dim3(8, 64), 256, 0, stream>>>(HH1b, fw2b, fb2, H2, out, nullptr, VPb, VNEW, 4096, 1024, 2048, 1 | 32);

  (void)in_sizes; (void)n_in; (void)out_size; (void)ws_size;
}